// Round 10
// baseline (274.683 us; speedup 1.0000x reference)
//
#include <hip/hip_runtime.h>

#define B_N 32
#define S_N 1024

typedef __attribute__((ext_vector_type(8))) short sh8;
typedef __attribute__((ext_vector_type(4))) short sh4;
typedef __attribute__((ext_vector_type(4))) float f4;

#define AS1 __attribute__((address_space(1)))
#define AS3 __attribute__((address_space(3)))

__device__ __forceinline__ short f2bf(float f) {
  unsigned u = __builtin_bit_cast(unsigned, f);
  u += 0x7fff + ((u >> 16) & 1);
  return (short)(u >> 16);
}
__device__ __forceinline__ float dot4(f4 a, f4 w) {
  return a.x * w.x + a.y * w.y + a.z * w.z + a.w * w.w;
}

// ---------- Phase 1a: Q projection + query mask (reads queries_it ONCE) ----------
__global__ __launch_bounds__(256) void proj_q_fused(
    const float* __restrict__ in, const float* __restrict__ W,
    const float* __restrict__ bias, short* __restrict__ out,
    float* __restrict__ qm) {
  __shared__ f4 w_lds[64][33];
  __shared__ f4 a_lds[64][33];
  const int tid = threadIdx.x;
  for (int e = tid; e < 64 * 32; e += 256) w_lds[e >> 5][e & 31] = ((const f4*)W)[e];
  const f4* inb = (const f4*)(in + (size_t)blockIdx.x * 64 * 128);
  for (int e = tid; e < 64 * 32; e += 256) a_lds[e >> 5][e & 31] = inb[e];
  __syncthreads();
  if (tid < 64) {
    float s = 0.f;
#pragma unroll
    for (int d = 0; d < 32; ++d) {
      f4 a = a_lds[tid][d];
      s += fabsf(a.x) + fabsf(a.y) + fabsf(a.z) + fabsf(a.w);
    }
    qm[blockIdx.x * 64 + tid] = (s != 0.f) ? 1.f : 0.f;
  }
  const int c1 = tid & 15, r4 = tid >> 4;
  float acc[4][4];
#pragma unroll
  for (int i = 0; i < 4; ++i)
#pragma unroll
    for (int k = 0; k < 4; ++k) acc[i][k] = 0.f;
#pragma unroll
  for (int d = 0; d < 32; ++d) {
    f4 w[4], a[4];
#pragma unroll
    for (int k = 0; k < 4; ++k) w[k] = w_lds[c1 + k * 16][d];
#pragma unroll
    for (int i = 0; i < 4; ++i) a[i] = a_lds[r4 * 4 + i][d];
#pragma unroll
    for (int i = 0; i < 4; ++i)
#pragma unroll
      for (int k = 0; k < 4; ++k) acc[i][k] += dot4(a[i], w[k]);
  }
  const size_t r0 = (size_t)blockIdx.x * 64;
#pragma unroll
  for (int i = 0; i < 4; ++i)
#pragma unroll
    for (int k = 0; k < 4; ++k)
      out[(r0 + r4 * 4 + i) * 64 + c1 + k * 16] = f2bf(acc[i][k] + bias[c1 + k * 16]);
}

// ---------- Phase 1b: K projection + V (both halves, transposed) + key mask ----------
__global__ __launch_bounds__(256) void proj_k_fused(
    const float* __restrict__ in,
    const float* __restrict__ Wk, const float* __restrict__ bk_,
    const float* __restrict__ Wv, const float* __restrict__ bv_,
    short* __restrict__ kit, short* __restrict__ vt, float* __restrict__ km) {
  __shared__ f4 w_lds[64][33];
  __shared__ f4 a_lds[64][33];
  __shared__ short tile[64][72];
  const int tid = threadIdx.x;
  const int c1 = tid & 15, r4 = tid >> 4;
  const f4* inb = (const f4*)(in + (size_t)blockIdx.x * 64 * 128);
  for (int e = tid; e < 64 * 32; e += 256) a_lds[e >> 5][e & 31] = inb[e];
  for (int e = tid; e < 64 * 32; e += 256) w_lds[e >> 5][e & 31] = ((const f4*)Wk)[e];
  __syncthreads();
  if (tid < 64) {
    float s = 0.f;
#pragma unroll
    for (int d = 0; d < 32; ++d) {
      f4 a = a_lds[tid][d];
      s += fabsf(a.x) + fabsf(a.y) + fabsf(a.z) + fabsf(a.w);
    }
    km[blockIdx.x * 64 + tid] = (s != 0.f) ? 1.f : 0.f;
  }
  {
    float acc[4][4];
#pragma unroll
    for (int i = 0; i < 4; ++i)
#pragma unroll
      for (int k = 0; k < 4; ++k) acc[i][k] = 0.f;
#pragma unroll
    for (int d = 0; d < 32; ++d) {
      f4 w[4], a[4];
#pragma unroll
      for (int k = 0; k < 4; ++k) w[k] = w_lds[c1 + k * 16][d];
#pragma unroll
      for (int i = 0; i < 4; ++i) a[i] = a_lds[r4 * 4 + i][d];
#pragma unroll
      for (int i = 0; i < 4; ++i)
#pragma unroll
        for (int k = 0; k < 4; ++k) acc[i][k] += dot4(a[i], w[k]);
    }
    const size_t r0 = (size_t)blockIdx.x * 64;
#pragma unroll
    for (int i = 0; i < 4; ++i)
#pragma unroll
      for (int k = 0; k < 4; ++k)
        kit[(r0 + r4 * 4 + i) * 64 + c1 + k * 16] = f2bf(acc[i][k] + bk_[c1 + k * 16]);
  }
  const int b = (blockIdx.x * 64) / S_N, s0 = (blockIdx.x * 64) % S_N;
#pragma unroll 1
  for (int ph = 0; ph < 2; ++ph) {
    __syncthreads();
    for (int e = tid; e < 64 * 32; e += 256)
      w_lds[e >> 5][e & 31] = ((const f4*)Wv)[ph * 64 * 32 + e];
    __syncthreads();
    float acc[4][4];
#pragma unroll
    for (int i = 0; i < 4; ++i)
#pragma unroll
      for (int k = 0; k < 4; ++k) acc[i][k] = 0.f;
#pragma unroll
    for (int d = 0; d < 32; ++d) {
      f4 w[4], a[4];
#pragma unroll
      for (int k = 0; k < 4; ++k) w[k] = w_lds[c1 + k * 16][d];
#pragma unroll
      for (int i = 0; i < 4; ++i) a[i] = a_lds[r4 * 4 + i][d];
#pragma unroll
      for (int i = 0; i < 4; ++i)
#pragma unroll
        for (int k = 0; k < 4; ++k) acc[i][k] += dot4(a[i], w[k]);
    }
#pragma unroll
    for (int i = 0; i < 4; ++i)
#pragma unroll
      for (int k = 0; k < 4; ++k)
        tile[c1 + k * 16][r4 * 4 + i] = f2bf(acc[i][k] + bv_[ph * 64 + c1 + k * 16]);
    __syncthreads();
    const int j = tid >> 2, seg = tid & 3;
    sh8 v0 = *(sh8*)&tile[j][seg * 16];
    sh8 v1 = *(sh8*)&tile[j][seg * 16 + 8];
    short* dst = vt + ((size_t)(b * 128 + ph * 64 + j)) * S_N + s0 + seg * 16;
    *(sh8*)dst = v0;
    *(sh8*)(dst + 8) = v1;
  }
}

// ---------- Phase 1c: ctx projections (DIN=64) ----------
__global__ __launch_bounds__(256) void proj_ctx(
    const float* __restrict__ in, const float* __restrict__ W,
    const float* __restrict__ bias, short* __restrict__ out) {
  constexpr int NS = 16;
  __shared__ f4 w_lds[64][NS + 1];
  __shared__ f4 a_lds[64][NS + 1];
  const int tid = threadIdx.x;
  for (int e = tid; e < 64 * NS; e += 256) w_lds[e / NS][e % NS] = ((const f4*)W)[e];
  const f4* inb = (const f4*)(in + (size_t)blockIdx.x * 64 * 64);
  for (int e = tid; e < 64 * NS; e += 256) a_lds[e / NS][e % NS] = inb[e];
  __syncthreads();
  const int c1 = tid & 15, r4 = tid >> 4;
  float acc[4][4];
#pragma unroll
  for (int i = 0; i < 4; ++i)
#pragma unroll
    for (int k = 0; k < 4; ++k) acc[i][k] = 0.f;
#pragma unroll
  for (int d = 0; d < NS; ++d) {
    f4 w[4], a[4];
#pragma unroll
    for (int k = 0; k < 4; ++k) w[k] = w_lds[c1 + k * 16][d];
#pragma unroll
    for (int i = 0; i < 4; ++i) a[i] = a_lds[r4 * 4 + i][d];
#pragma unroll
    for (int i = 0; i < 4; ++i)
#pragma unroll
      for (int k = 0; k < 4; ++k) acc[i][k] += dot4(a[i], w[k]);
  }
  const size_t r0 = (size_t)blockIdx.x * 64;
#pragma unroll
  for (int i = 0; i < 4; ++i)
#pragma unroll
    for (int k = 0; k < 4; ++k)
      out[(r0 + r4 * 4 + i) * 64 + c1 + k * 16] = f2bf(acc[i][k] + bias[c1 + k * 16]);
}

// ---------- Phase 2: fused attention, ALL streams staged via global_load_lds ----------
// Grid: 512 blocks (XCD-swizzled), 4 waves; block = 64 q-rows (16/wave), all
// 1024 keys in 64-key chunks. Per chunk, 64 direct-to-LDS loads (1 KB each,
// 16/wave) stage K, kctx, V AND the noise tile (fixes R9's 16-line noise
// gathers — the dominant request-rate bottleneck). Swizzle applied on the
// GLOBAL source address (linear LDS dest — rule #21): 8-slot XOR (row&7) for
// K/V, 16-slot XOR (row&15) for noise. No staging VGPRs, no ds_writes.
// Logits ~1e-3 by construction => fixed softmax max 0 is safe.
__global__ __launch_bounds__(256, 2) void attn_kernel(
    const short* __restrict__ qit, const short* __restrict__ kit,
    const short* __restrict__ qctx, const short* __restrict__ kctx,
    const short* __restrict__ vt,     // [B,128,S] bf16
    const float* __restrict__ noise,  // [B,2,S,S]
    const float* __restrict__ sigma,  // [B,2]
    const float* __restrict__ qmask, const float* __restrict__ kmask,  // [B,S]
    const float* __restrict__ qin,    // queries_it [B,S,128]
    const float* __restrict__ W1, const float* __restrict__ b1,
    const float* __restrict__ W2, const float* __restrict__ b2,
    float* __restrict__ out) {
  // staging arena (16B units): arena = kit rows 0-63 / kctx rows 64-127 (16KB),
  // vt_lds [128][64] (16KB), nz_lds [2 heads][64 q][64 k] f32 (32KB).
  __shared__ __align__(16) short arena[128][64];
  __shared__ __align__(16) short vt_lds[128][64];
  __shared__ __align__(16) float nz_lds[2][64][64];
  __shared__ float lsum_lds[4][2][16];

  const int tid = threadIdx.x;
  const int wave = tid >> 6, lane = tid & 63;
  const int bid = blockIdx.x;
  const int wg = ((bid & 7) << 6) | (bid >> 3);  // XCD swizzle (512 % 8 == 0)
  const int b = wg >> 4, qt = wg & 15;
  const int qblk = qt * 64;
  const int qbase = qblk + wave * 16;
  const int col = lane & 15, grp = lane >> 4;

  const float w100 = W1[0], w101 = W1[1], w110 = W1[2], w111 = W1[3];
  const float bb10 = b1[0], bb11 = b1[1];
  const float sc = 0.125f;
  const float w200 = W2[0] * sc, w201 = W2[1] * sc, w210 = W2[2] * sc, w211 = W2[3] * sc;
  const float bb20 = b2[0] * sc, bb21 = b2[1] * sc;
  float sg0 = sigma[b * 2 + 0]; sg0 *= sg0;
  float sg1 = sigma[b * 2 + 1]; sg1 *= sg1;

  // Q fragments (B-operand of swapped QK^T): q = col, d = grp*8 + t*32
  const int qrow = qbase + col;
  sh8 aqit[2], aqctx[2];
#pragma unroll
  for (int t = 0; t < 2; ++t) {
    aqit[t] = *(const sh8*)(qit + ((size_t)(b * S_N + qrow)) * 64 + grp * 8 + t * 32);
    aqctx[t] = *(const sh8*)(qctx + ((size_t)(b * S_N + qrow)) * 64 + grp * 8 + t * 32);
  }

  f4 acc[2][4];
#pragma unroll
  for (int h = 0; h < 2; ++h)
#pragma unroll
    for (int dt = 0; dt < 4; ++dt) acc[h][dt] = (f4)0.f;
  float rs0 = 0.f, rs1 = 0.f;

  const float* nz_g = noise + (size_t)(b * 2) * S_N * S_N;
  const float* kmb = kmask + b * S_N + grp * 4;
  const short* kit_g = kit + (size_t)b * S_N * 64;
  const short* kctx_g = kctx + (size_t)b * S_N * 64;
  const short* vt_g = vt + (size_t)b * 128 * S_N;
  short* ar = &arena[0][0];
  short* vl = &vt_lds[0][0];
  const int sw_key = col & 7;

#pragma unroll 1
  for (int kc = 0; kc < S_N; kc += 64) {
    // --- staging: 64 x 1KB direct-to-LDS, 16 insts/wave, source pre-swizzled
#pragma unroll
    for (int jj = 0; jj < 16; ++jj) {
      const int j = (wave << 4) + jj;
      const int u = (j << 6) + lane;
      const void* g;
      void* l;
      if (j < 8) {  // kit tile: 8KB
        const int row = u >> 3, sl = u & 7;
        g = (const void*)(kit_g + (size_t)(kc + row) * 64 + ((sl ^ (row & 7)) << 3));
        l = (void*)((char*)ar + j * 1024);
      } else if (j < 16) {  // kctx tile: 8KB
        const int v = u - 512, row = v >> 3, sl = v & 7;
        g = (const void*)(kctx_g + (size_t)(kc + row) * 64 + ((sl ^ (row & 7)) << 3));
        l = (void*)((char*)ar + j * 1024);
      } else if (j < 32) {  // vt tile: 16KB
        const int v = u - 1024, d = v >> 3, sl = v & 7;
        g = (const void*)(vt_g + (size_t)d * S_N + kc + ((sl ^ (d & 7)) << 3));
        l = (void*)((char*)vl + (j - 16) * 1024);
      } else {  // noise tile: 32KB (head = bit 10)
        const int n = u - 2048, head = n >> 10, r2 = (n >> 4) & 63, sl = n & 15;
        g = (const void*)(nz_g + (size_t)head * S_N * S_N + (size_t)(qblk + r2) * S_N + kc +
                          ((sl ^ (r2 & 15)) << 2));
        l = (void*)((char*)&nz_lds[0][0][0] + (j - 32) * 1024);
      }
      __builtin_amdgcn_global_load_lds((const AS1 unsigned*)g, (AS3 unsigned*)l, 16, 0, 0);
    }
    __syncthreads();  // barA: tiles visible (compiler drains vmcnt)

    // --- QK^T (swapped): C = S^T, k = grp*4+r, q = col
    f4 sit[4], sctx[4];
#pragma unroll
    for (int kt = 0; kt < 4; ++kt) {
      const int krow = kt * 16 + col;
      sit[kt] = (f4)0.f;
      sctx[kt] = (f4)0.f;
#pragma unroll
      for (int t = 0; t < 2; ++t) {
        const int so = ((grp + 4 * t) ^ sw_key) * 8;
        sh8 bk = *(const sh8*)&ar[krow * 64 + so];
        sit[kt] = __builtin_amdgcn_mfma_f32_16x16x32_bf16(bk, aqit[t], sit[kt], 0, 0, 0);
        sh8 bc = *(const sh8*)&ar[(64 + krow) * 64 + so];
        sctx[kt] = __builtin_amdgcn_mfma_f32_16x16x32_bf16(bc, aqctx[t], sctx[kt], 0, 0, 0);
      }
    }
    __syncthreads();  // barB: QK reads done -> arena reusable as P

    // --- MLP + exp + mask; noise from LDS; P -> arena (swizzled, PV-A layout)
    const int prow0 = (wave << 5) + col;
    const float* nz0 = &nz_lds[0][wave * 16 + col][0];
    const float* nz1 = &nz_lds[1][wave * 16 + col][0];
#pragma unroll
    for (int kt = 0; kt < 4; ++kt) {
      const int nso = ((kt * 4 + grp) ^ col) << 2;
      f4 n0 = *(const f4*)(nz0 + nso);
      f4 n1 = *(const f4*)(nz1 + nso);
      f4 km = *(const f4*)(kmb + kc + kt * 16);
      sh4 po, pc;
#pragma unroll
      for (int r = 0; r < 4; ++r) {
        float x0 = fmaf(n0[r], sg0, sit[kt][r]);
        float x1 = fmaf(n1[r], sg1, sctx[kt][r]);
        float h0 = fmaxf(fmaf(w101, x1, fmaf(w100, x0, bb10)), 0.f);
        float h1 = fmaxf(fmaf(w111, x1, fmaf(w110, x0, bb11)), 0.f);
        float L0 = fmaf(w201, h1, fmaf(w200, h0, bb20));
        float L1 = fmaf(w211, h1, fmaf(w210, h0, bb21));
        float p0 = __expf(L0) * km[r];
        float p1 = __expf(L1) * km[r];
        rs0 += p0;
        rs1 += p1;
        po[r] = f2bf(p0);
        pc[r] = f2bf(p1);
      }
      const int sl = kt * 2 + (grp >> 1);
      const int off = ((sl ^ sw_key) * 8) + (grp & 1) * 4;
      *(sh4*)&ar[prow0 * 64 + off] = po;
      *(sh4*)&ar[(prow0 + 16) * 64 + off] = pc;
    }
    // --- PV: A = P (own wave region), B = V tile
#pragma unroll
    for (int h = 0; h < 2; ++h) {
#pragma unroll
      for (int t = 0; t < 2; ++t) {
        const int so = ((grp + 4 * t) ^ sw_key) * 8;
        sh8 pa = *(const sh8*)&ar[(prow0 + h * 16) * 64 + so];
#pragma unroll
        for (int dt = 0; dt < 4; ++dt) {
          const int drow = h * 64 + dt * 16 + col;
          sh8 bv = *(const sh8*)&vl[drow * 64 + so];
          acc[h][dt] = __builtin_amdgcn_mfma_f32_16x16x32_bf16(pa, bv, acc[h][dt], 0, 0, 0);
        }
      }
    }
    __syncthreads();  // barC: all LDS reads done -> next chunk may overwrite
  }

  // sum-exp: reduce over the 4 lanes sharing q=col, redistribute via LDS
  rs0 += __shfl_xor(rs0, 16); rs0 += __shfl_xor(rs0, 32);
  rs1 += __shfl_xor(rs1, 16); rs1 += __shfl_xor(rs1, 32);
  if (lane < 16) {
    lsum_lds[wave][0][col] = rs0;
    lsum_lds[wave][1][col] = rs1;
  }
  __syncthreads();
  f4 ls0 = *(const f4*)&lsum_lds[wave][0][grp * 4];
  f4 ls1 = *(const f4*)&lsum_lds[wave][1][grp * 4];
  f4 qm4 = *(const f4*)(qmask + (size_t)b * S_N + qbase + grp * 4);
#pragma unroll
  for (int h = 0; h < 2; ++h)
#pragma unroll
    for (int dt = 0; dt < 4; ++dt)
#pragma unroll
      for (int r = 0; r < 4; ++r) {
        const float s2 = qm4[r] / (h ? ls1[r] : ls0[r]);
        const size_t o = ((size_t)(b * S_N + qbase + grp * 4 + r)) * 128 + h * 64 + dt * 16 + col;
        out[o] = acc[h][dt][r] * s2 + qin[o];
      }
}

extern "C" void kernel_launch(void* const* d_in, const int* in_sizes, int n_in,
                              void* d_out, int out_size, void* d_ws, size_t ws_size,
                              hipStream_t stream) {
  const float* queries_it = (const float*)d_in[0];
  const float* queries_ctx = (const float*)d_in[1];
  const float* keys_it = (const float*)d_in[2];
  const float* keys_ctx = (const float*)d_in[3];
  const float* sigma = (const float*)d_in[4];
  const float* noise = (const float*)d_in[5];
  const float* Wq_it = (const float*)d_in[6];
  const float* bq_it = (const float*)d_in[7];
  const float* Wk_it = (const float*)d_in[8];
  const float* bk_it = (const float*)d_in[9];
  const float* Wq_ctx = (const float*)d_in[10];
  const float* bq_ctx = (const float*)d_in[11];
  const float* Wk_ctx = (const float*)d_in[12];
  const float* bk_ctx = (const float*)d_in[13];
  const float* Wv = (const float*)d_in[14];
  const float* bv = (const float*)d_in[15];
  const float* W1 = (const float*)d_in[16];
  const float* b1 = (const float*)d_in[17];
  const float* W2 = (const float*)d_in[18];
  const float* b2 = (const float*)d_in[19];
  float* out = (float*)d_out;

  char* ws = (char*)d_ws;
  short* qit = (short*)(ws);                    // 4 MB
  short* kit = (short*)(ws + (4ull << 20));     // 4 MB
  short* qctx = (short*)(ws + (8ull << 20));    // 4 MB
  short* kctx = (short*)(ws + (12ull << 20));   // 4 MB
  short* vt = (short*)(ws + (16ull << 20));     // 8 MB  [B,128,S]
  float* qmask = (float*)(ws + (24ull << 20));  // 128 KB
  float* kmask = (float*)(ws + (24ull << 20) + (size_t)B_N * S_N * 4);

  const int NR = B_N * S_N;
  proj_q_fused<<<dim3(NR / 64), 256, 0, stream>>>(queries_it, Wq_it, bq_it, qit, qmask);
  proj_k_fused<<<dim3(NR / 64), 256, 0, stream>>>(keys_it, Wk_it, bk_it, Wv, bv, kit, vt, kmask);
  proj_ctx<<<dim3(NR / 64), 256, 0, stream>>>(queries_ctx, Wq_ctx, bq_ctx, qctx);
  proj_ctx<<<dim3(NR / 64), 256, 0, stream>>>(keys_ctx, Wk_ctx, bk_ctx, kctx);

  attn_kernel<<<dim3(B_N * (S_N / 64)), 256, 0, stream>>>(
      qit, kit, qctx, kctx, vt, noise, sigma, qmask, kmask, queries_it,
      W1, b1, W2, b2, out);
}

// Round 11
// 187.208 us; speedup vs baseline: 1.4673x; 1.4673x over previous
//
#include <hip/hip_runtime.h>

#define B_N 32
#define S_N 1024

typedef __attribute__((ext_vector_type(8))) short sh8;
typedef __attribute__((ext_vector_type(4))) short sh4;
typedef __attribute__((ext_vector_type(4))) float f4;

#define AS1 __attribute__((address_space(1)))
#define AS3 __attribute__((address_space(3)))

__device__ __forceinline__ short f2bf(float f) {
  unsigned u = __builtin_bit_cast(unsigned, f);
  u += 0x7fff + ((u >> 16) & 1);
  return (short)(u >> 16);
}
__device__ __forceinline__ float dot4(f4 a, f4 w) {
  return a.x * w.x + a.y * w.y + a.z * w.z + a.w * w.w;
}

// ---------- Phase 1a: Q projection + query mask (reads queries_it ONCE) ----------
__global__ __launch_bounds__(256) void proj_q_fused(
    const float* __restrict__ in, const float* __restrict__ W,
    const float* __restrict__ bias, short* __restrict__ out,
    float* __restrict__ qm) {
  __shared__ f4 w_lds[64][33];
  __shared__ f4 a_lds[64][33];
  const int tid = threadIdx.x;
  for (int e = tid; e < 64 * 32; e += 256) w_lds[e >> 5][e & 31] = ((const f4*)W)[e];
  const f4* inb = (const f4*)(in + (size_t)blockIdx.x * 64 * 128);
  for (int e = tid; e < 64 * 32; e += 256) a_lds[e >> 5][e & 31] = inb[e];
  __syncthreads();
  if (tid < 64) {
    float s = 0.f;
#pragma unroll
    for (int d = 0; d < 32; ++d) {
      f4 a = a_lds[tid][d];
      s += fabsf(a.x) + fabsf(a.y) + fabsf(a.z) + fabsf(a.w);
    }
    qm[blockIdx.x * 64 + tid] = (s != 0.f) ? 1.f : 0.f;
  }
  const int c1 = tid & 15, r4 = tid >> 4;
  float acc[4][4];
#pragma unroll
  for (int i = 0; i < 4; ++i)
#pragma unroll
    for (int k = 0; k < 4; ++k) acc[i][k] = 0.f;
#pragma unroll
  for (int d = 0; d < 32; ++d) {
    f4 w[4], a[4];
#pragma unroll
    for (int k = 0; k < 4; ++k) w[k] = w_lds[c1 + k * 16][d];
#pragma unroll
    for (int i = 0; i < 4; ++i) a[i] = a_lds[r4 * 4 + i][d];
#pragma unroll
    for (int i = 0; i < 4; ++i)
#pragma unroll
      for (int k = 0; k < 4; ++k) acc[i][k] += dot4(a[i], w[k]);
  }
  const size_t r0 = (size_t)blockIdx.x * 64;
#pragma unroll
  for (int i = 0; i < 4; ++i)
#pragma unroll
    for (int k = 0; k < 4; ++k)
      out[(r0 + r4 * 4 + i) * 64 + c1 + k * 16] = f2bf(acc[i][k] + bias[c1 + k * 16]);
}

// ---------- Phase 1b: K projection + V (both halves, transposed) + key mask ----------
__global__ __launch_bounds__(256) void proj_k_fused(
    const float* __restrict__ in,
    const float* __restrict__ Wk, const float* __restrict__ bk_,
    const float* __restrict__ Wv, const float* __restrict__ bv_,
    short* __restrict__ kit, short* __restrict__ vt, float* __restrict__ km) {
  __shared__ f4 w_lds[64][33];
  __shared__ f4 a_lds[64][33];
  __shared__ short tile[64][72];
  const int tid = threadIdx.x;
  const int c1 = tid & 15, r4 = tid >> 4;
  const f4* inb = (const f4*)(in + (size_t)blockIdx.x * 64 * 128);
  for (int e = tid; e < 64 * 32; e += 256) a_lds[e >> 5][e & 31] = inb[e];
  for (int e = tid; e < 64 * 32; e += 256) w_lds[e >> 5][e & 31] = ((const f4*)Wk)[e];
  __syncthreads();
  if (tid < 64) {
    float s = 0.f;
#pragma unroll
    for (int d = 0; d < 32; ++d) {
      f4 a = a_lds[tid][d];
      s += fabsf(a.x) + fabsf(a.y) + fabsf(a.z) + fabsf(a.w);
    }
    km[blockIdx.x * 64 + tid] = (s != 0.f) ? 1.f : 0.f;
  }
  {
    float acc[4][4];
#pragma unroll
    for (int i = 0; i < 4; ++i)
#pragma unroll
      for (int k = 0; k < 4; ++k) acc[i][k] = 0.f;
#pragma unroll
    for (int d = 0; d < 32; ++d) {
      f4 w[4], a[4];
#pragma unroll
      for (int k = 0; k < 4; ++k) w[k] = w_lds[c1 + k * 16][d];
#pragma unroll
      for (int i = 0; i < 4; ++i) a[i] = a_lds[r4 * 4 + i][d];
#pragma unroll
      for (int i = 0; i < 4; ++i)
#pragma unroll
        for (int k = 0; k < 4; ++k) acc[i][k] += dot4(a[i], w[k]);
    }
    const size_t r0 = (size_t)blockIdx.x * 64;
#pragma unroll
    for (int i = 0; i < 4; ++i)
#pragma unroll
      for (int k = 0; k < 4; ++k)
        kit[(r0 + r4 * 4 + i) * 64 + c1 + k * 16] = f2bf(acc[i][k] + bk_[c1 + k * 16]);
  }
  const int b = (blockIdx.x * 64) / S_N, s0 = (blockIdx.x * 64) % S_N;
#pragma unroll 1
  for (int ph = 0; ph < 2; ++ph) {
    __syncthreads();
    for (int e = tid; e < 64 * 32; e += 256)
      w_lds[e >> 5][e & 31] = ((const f4*)Wv)[ph * 64 * 32 + e];
    __syncthreads();
    float acc[4][4];
#pragma unroll
    for (int i = 0; i < 4; ++i)
#pragma unroll
      for (int k = 0; k < 4; ++k) acc[i][k] = 0.f;
#pragma unroll
    for (int d = 0; d < 32; ++d) {
      f4 w[4], a[4];
#pragma unroll
      for (int k = 0; k < 4; ++k) w[k] = w_lds[c1 + k * 16][d];
#pragma unroll
      for (int i = 0; i < 4; ++i) a[i] = a_lds[r4 * 4 + i][d];
#pragma unroll
      for (int i = 0; i < 4; ++i)
#pragma unroll
        for (int k = 0; k < 4; ++k) acc[i][k] += dot4(a[i], w[k]);
    }
#pragma unroll
    for (int i = 0; i < 4; ++i)
#pragma unroll
      for (int k = 0; k < 4; ++k)
        tile[c1 + k * 16][r4 * 4 + i] = f2bf(acc[i][k] + bv_[ph * 64 + c1 + k * 16]);
    __syncthreads();
    const int j = tid >> 2, seg = tid & 3;
    sh8 v0 = *(sh8*)&tile[j][seg * 16];
    sh8 v1 = *(sh8*)&tile[j][seg * 16 + 8];
    short* dst = vt + ((size_t)(b * 128 + ph * 64 + j)) * S_N + s0 + seg * 16;
    *(sh8*)dst = v0;
    *(sh8*)(dst + 8) = v1;
  }
}

// ---------- Phase 1c: ctx projections (DIN=64) ----------
__global__ __launch_bounds__(256) void proj_ctx(
    const float* __restrict__ in, const float* __restrict__ W,
    const float* __restrict__ bias, short* __restrict__ out) {
  constexpr int NS = 16;
  __shared__ f4 w_lds[64][NS + 1];
  __shared__ f4 a_lds[64][NS + 1];
  const int tid = threadIdx.x;
  for (int e = tid; e < 64 * NS; e += 256) w_lds[e / NS][e % NS] = ((const f4*)W)[e];
  const f4* inb = (const f4*)(in + (size_t)blockIdx.x * 64 * 64);
  for (int e = tid; e < 64 * NS; e += 256) a_lds[e / NS][e % NS] = inb[e];
  __syncthreads();
  const int c1 = tid & 15, r4 = tid >> 4;
  float acc[4][4];
#pragma unroll
  for (int i = 0; i < 4; ++i)
#pragma unroll
    for (int k = 0; k < 4; ++k) acc[i][k] = 0.f;
#pragma unroll
  for (int d = 0; d < NS; ++d) {
    f4 w[4], a[4];
#pragma unroll
    for (int k = 0; k < 4; ++k) w[k] = w_lds[c1 + k * 16][d];
#pragma unroll
    for (int i = 0; i < 4; ++i) a[i] = a_lds[r4 * 4 + i][d];
#pragma unroll
    for (int i = 0; i < 4; ++i)
#pragma unroll
      for (int k = 0; k < 4; ++k) acc[i][k] += dot4(a[i], w[k]);
  }
  const size_t r0 = (size_t)blockIdx.x * 64;
#pragma unroll
  for (int i = 0; i < 4; ++i)
#pragma unroll
    for (int k = 0; k < 4; ++k)
      out[(r0 + r4 * 4 + i) * 64 + c1 + k * 16] = f2bf(acc[i][k] + bias[c1 + k * 16]);
}

// ---------- Phase 2: fused attention, double-buffered pipeline ----------
// Grid: 512 blocks (XCD-swizzled), 4 waves; block = 64 q-rows, 32 chunks of
// 32 keys. Per-chunk LDS buffer (32 KB): K 4K | kctx 4K | V 8K | noise 16K,
// double-buffered. Pipeline per chunk k:
//   __syncthreads()            — drains stage(k) [issued LAST iteration, so
//                                its latency was hidden under compute(k-1)]
//   STAGE(buf^1, k+1)          — 8 global_load_lds per wave, stays in flight
//                                across ALL of compute(k) (no drain until the
//                                next top __syncthreads)
//   QK(buf) ; raw s_barrier ; MLP+P->buf(K overlay) ; PV(buf)
// Swizzles on the GLOBAL source address (linear LDS dest, rule #21); all
// consumer read patterns are uniform over bank-groups (verified 8 lanes x 16B
// per 4-bank group = LDS issue floor). kmask preloaded to LDS so the steady-
// state vmem FIFO holds ONLY the 8 stage loads.
// Logits ~1e-3 by construction => fixed softmax max 0 is safe.
__global__ __launch_bounds__(256, 2) void attn_kernel(
    const short* __restrict__ qit, const short* __restrict__ kit,
    const short* __restrict__ qctx, const short* __restrict__ kctx,
    const short* __restrict__ vt,     // [B,128,S] bf16
    const float* __restrict__ noise,  // [B,2,S,S]
    const float* __restrict__ sigma,  // [B,2]
    const float* __restrict__ qmask, const float* __restrict__ kmask,  // [B,S]
    const float* __restrict__ qin,    // queries_it [B,S,128]
    const float* __restrict__ W1, const float* __restrict__ b1,
    const float* __restrict__ W2, const float* __restrict__ b2,
    float* __restrict__ out) {
  __shared__ __align__(16) char bufs[2][32768];
  __shared__ float kml[1024];
  __shared__ float lsum_lds[4][2][16];

  const int tid = threadIdx.x;
  const int wave = tid >> 6, lane = tid & 63;
  const int bid = blockIdx.x;
  const int wg = ((bid & 7) << 6) | (bid >> 3);  // XCD swizzle (512 % 8 == 0)
  const int b = wg >> 4, qt = wg & 15;
  const int qblk = qt * 64;
  const int qbase = qblk + wave * 16;
  const int col = lane & 15, grp = lane >> 4;
  const int sw_key = col & 7;

  const float w100 = W1[0], w101 = W1[1], w110 = W1[2], w111 = W1[3];
  const float bb10 = b1[0], bb11 = b1[1];
  const float sc = 0.125f;
  const float w200 = W2[0] * sc, w201 = W2[1] * sc, w210 = W2[2] * sc, w211 = W2[3] * sc;
  const float bb20 = b2[0] * sc, bb21 = b2[1] * sc;
  float sg0 = sigma[b * 2 + 0]; sg0 *= sg0;
  float sg1 = sigma[b * 2 + 1]; sg1 *= sg1;

  // Q fragments (B-operand of swapped QK^T): q = col, d = grp*8 + t*32
  const int qrow = qbase + col;
  sh8 aqit[2], aqctx[2];
#pragma unroll
  for (int t = 0; t < 2; ++t) {
    aqit[t] = *(const sh8*)(qit + ((size_t)(b * S_N + qrow)) * 64 + grp * 8 + t * 32);
    aqctx[t] = *(const sh8*)(qctx + ((size_t)(b * S_N + qrow)) * 64 + grp * 8 + t * 32);
  }

  f4 acc[2][4];
#pragma unroll
  for (int h = 0; h < 2; ++h)
#pragma unroll
    for (int dt = 0; dt < 4; ++dt) acc[h][dt] = (f4)0.f;
  float rs0 = 0.f, rs1 = 0.f;

  const float* nz_g = noise + (size_t)(b * 2) * S_N * S_N;
  const short* kit_g = kit + (size_t)b * S_N * 64;
  const short* kctx_g = kctx + (size_t)b * S_N * 64;
  const short* vt_g = vt + (size_t)b * 128 * S_N;

  // kmask -> LDS once (keeps the steady-state vmem FIFO = stage loads only)
  for (int i = tid; i < 1024; i += 256) kml[i] = kmask[(size_t)b * S_N + i];

  // STAGE one 32-key chunk into buf: per wave 8 global_load_lds (1 KB each).
  // Units: kit u=wave | kctx u=wave | V u=2w,2w+1 | noise u=4w..4w+3.
  auto STAGE = [&](char* buf, int kc) {
    {  // kit: [32 rows][8 slots of 8 shorts], swz slot^(row&7)
      const int u = wave * 64 + lane, row = u >> 3, sl = u & 7;
      const short* g = kit_g + (size_t)(kc + row) * 64 + ((sl ^ (row & 7)) << 3);
      __builtin_amdgcn_global_load_lds((const AS1 unsigned*)g, (AS3 unsigned*)(buf + wave * 1024), 16, 0, 0);
    }
    {  // kctx
      const int u = wave * 64 + lane, row = u >> 3, sl = u & 7;
      const short* g = kctx_g + (size_t)(kc + row) * 64 + ((sl ^ (row & 7)) << 3);
      __builtin_amdgcn_global_load_lds((const AS1 unsigned*)g, (AS3 unsigned*)(buf + 4096 + wave * 1024), 16, 0, 0);
    }
#pragma unroll
    for (int i = 0; i < 2; ++i) {  // V: [128 d][4 slots of 8 shorts], swz slot^(d&3)
      const int un = 2 * wave + i;
      const int v = un * 64 + lane, d = v >> 2, sl = v & 3;
      const short* g = vt_g + (size_t)d * S_N + kc + ((sl ^ (d & 3)) << 3);
      __builtin_amdgcn_global_load_lds((const AS1 unsigned*)g, (AS3 unsigned*)(buf + 8192 + un * 1024), 16, 0, 0);
    }
#pragma unroll
    for (int i = 0; i < 4; ++i) {  // noise: [2 head][64 q][8 slots of f4], swz slot^(q&7)
      const int un = 4 * wave + i;
      const int n = un * 64 + lane, r16 = n >> 3, head = r16 >> 6, q = r16 & 63, sl = n & 7;
      const float* g = nz_g + (size_t)head * S_N * S_N + (size_t)(qblk + q) * S_N + kc + ((sl ^ (q & 7)) << 2);
      __builtin_amdgcn_global_load_lds((const AS1 unsigned*)g, (AS3 unsigned*)(buf + 16384 + un * 1024), 16, 0, 0);
    }
  };

  STAGE(bufs[0], 0);  // prologue

#pragma unroll 1
  for (int kcc = 0; kcc < 32; ++kcc) {
    const int kc = kcc * 32;
    char* cur = bufs[0] + (size_t)(kcc & 1) * 32768;
    char* nxt = bufs[0] + (size_t)((kcc & 1) ^ 1) * 32768;
    __syncthreads();  // drains stage(kcc) (landed during compute(kcc-1)); also
                      // guards buf reuse: all waves done reading `nxt`'s old data
    if (kcc + 1 < 32) STAGE(nxt, kc + 32);

    const short* Kb = (const short*)cur;
    const short* Cb = (const short*)(cur + 4096);
    const short* Vb = (const short*)(cur + 8192);
    const float* Nb = (const float*)(cur + 16384);

    // --- QK^T (swapped): C = S^T, k = kt*16 + grp*4 + r, q = col
    f4 sit[2], sctx[2];
#pragma unroll
    for (int kt = 0; kt < 2; ++kt) {
      const int krow = kt * 16 + col;
      sit[kt] = (f4)0.f;
      sctx[kt] = (f4)0.f;
#pragma unroll
      for (int t = 0; t < 2; ++t) {
        const int so = ((grp + 4 * t) ^ sw_key) * 8;
        sh8 bk = *(const sh8*)&Kb[krow * 64 + so];
        sit[kt] = __builtin_amdgcn_mfma_f32_16x16x32_bf16(bk, aqit[t], sit[kt], 0, 0, 0);
        sh8 bc = *(const sh8*)&Cb[krow * 64 + so];
        sctx[kt] = __builtin_amdgcn_mfma_f32_16x16x32_bf16(bc, aqctx[t], sctx[kt], 0, 0, 0);
      }
    }
    // mid barrier: all QK reads of K/kctx done -> region reusable as P.
    // RAW s_barrier (no vmcnt drain — stage(k+1) must stay in flight!)
    asm volatile("" ::: "memory");
    __builtin_amdgcn_s_barrier();
    asm volatile("" ::: "memory");

    // --- MLP + exp + mask; P (bf16) -> K-region overlay [128 rows][32 shorts]
    short* Pb = (short*)cur;
    const int qrl = wave * 16 + col;
    const int prow0 = wave * 32 + col;
#pragma unroll
    for (int kt = 0; kt < 2; ++kt) {
      const int nsl = ((kt * 4 + grp) ^ sw_key) * 4;
      f4 n0 = *(const f4*)&Nb[(size_t)qrl * 32 + nsl];
      f4 n1 = *(const f4*)&Nb[(size_t)(64 + qrl) * 32 + nsl];
      f4 km = *(const f4*)&kml[kc + kt * 16 + grp * 4];
      sh4 po, pc;
#pragma unroll
      for (int r = 0; r < 4; ++r) {
        float x0 = fmaf(n0[r], sg0, sit[kt][r]);
        float x1 = fmaf(n1[r], sg1, sctx[kt][r]);
        float h0 = fmaxf(fmaf(w101, x1, fmaf(w100, x0, bb10)), 0.f);
        float h1 = fmaxf(fmaf(w111, x1, fmaf(w110, x0, bb11)), 0.f);
        float L0 = fmaf(w201, h1, fmaf(w200, h0, bb20));
        float L1 = fmaf(w211, h1, fmaf(w210, h0, bb21));
        float p0 = __expf(L0) * km[r];
        float p1 = __expf(L1) * km[r];
        rs0 += p0;
        rs1 += p1;
        po[r] = f2bf(p0);
        pc[r] = f2bf(p1);
      }
      const int sl8 = kt * 2 + (grp >> 1);
      const int off0 = ((sl8 ^ (prow0 & 3)) * 8) + (grp & 1) * 4;
      const int prow1 = prow0 + 16;
      const int off1 = ((sl8 ^ (prow1 & 3)) * 8) + (grp & 1) * 4;
      *(sh4*)&Pb[prow0 * 32 + off0] = po;
      *(sh4*)&Pb[prow1 * 32 + off1] = pc;
    }
    // --- PV: A = P (own wave's rows; intra-wave LDS write->read is in-order),
    //         B = V tile. One MFMA per (h,dt): K=32 matches chunk exactly.
#pragma unroll
    for (int h = 0; h < 2; ++h) {
      const int prow = wave * 32 + h * 16 + col;
      sh8 pa = *(const sh8*)&Pb[prow * 32 + ((grp ^ (prow & 3)) * 8)];
#pragma unroll
      for (int dt = 0; dt < 4; ++dt) {
        const int drow = h * 64 + dt * 16 + col;
        sh8 bv = *(const sh8*)&Vb[drow * 32 + ((grp ^ (drow & 3)) * 8)];
        acc[h][dt] = __builtin_amdgcn_mfma_f32_16x16x32_bf16(pa, bv, acc[h][dt], 0, 0, 0);
      }
    }
  }

  // sum-exp: reduce over the 4 lanes sharing q=col, redistribute via LDS
  rs0 += __shfl_xor(rs0, 16); rs0 += __shfl_xor(rs0, 32);
  rs1 += __shfl_xor(rs1, 16); rs1 += __shfl_xor(rs1, 32);
  if (lane < 16) {
    lsum_lds[wave][0][col] = rs0;
    lsum_lds[wave][1][col] = rs1;
  }
  __syncthreads();
  f4 ls0 = *(const f4*)&lsum_lds[wave][0][grp * 4];
  f4 ls1 = *(const f4*)&lsum_lds[wave][1][grp * 4];
  f4 qm4 = *(const f4*)(qmask + (size_t)b * S_N + qbase + grp * 4);
#pragma unroll
  for (int h = 0; h < 2; ++h)
#pragma unroll
    for (int dt = 0; dt < 4; ++dt)
#pragma unroll
      for (int r = 0; r < 4; ++r) {
        const float s2 = qm4[r] / (h ? ls1[r] : ls0[r]);
        const size_t o = ((size_t)(b * S_N + qbase + grp * 4 + r)) * 128 + h * 64 + dt * 16 + col;
        out[o] = acc[h][dt][r] * s2 + qin[o];
      }
}

extern "C" void kernel_launch(void* const* d_in, const int* in_sizes, int n_in,
                              void* d_out, int out_size, void* d_ws, size_t ws_size,
                              hipStream_t stream) {
  const float* queries_it = (const float*)d_in[0];
  const float* queries_ctx = (const float*)d_in[1];
  const float* keys_it = (const float*)d_in[2];
  const float* keys_ctx = (const float*)d_in[3];
  const float* sigma = (const float*)d_in[4];
  const float* noise = (const float*)d_in[5];
  const float* Wq_it = (const float*)d_in[6];
  const float* bq_it = (const float*)d_in[7];
  const float* Wk_it = (const float*)d_in[8];
  const float* bk_it = (const float*)d_in[9];
  const float* Wq_ctx = (const float*)d_in[10];
  const float* bq_ctx = (const float*)d_in[11];
  const float* Wk_ctx = (const float*)d_in[12];
  const float* bk_ctx = (const float*)d_in[13];
  const float* Wv = (const float*)d_in[14];
  const float* bv = (const float*)d_in[15];
  const float* W1 = (const float*)d_in[16];
  const float* b1 = (const float*)d_in[17];
  const float* W2 = (const float*)d_in[18];
  const float* b2 = (const float*)d_in[19];
  float* out = (float*)d_out;

  char* ws = (char*)d_ws;
  short* qit = (short*)(ws);                    // 4 MB
  short* kit = (short*)(ws + (4ull << 20));     // 4 MB
  short* qctx = (short*)(ws + (8ull << 20));    // 4 MB
  short* kctx = (short*)(ws + (12ull << 20));   // 4 MB
  short* vt = (short*)(ws + (16ull << 20));     // 8 MB  [B,128,S]
  float* qmask = (float*)(ws + (24ull << 20));  // 128 KB
  float* kmask = (float*)(ws + (24ull << 20) + (size_t)B_N * S_N * 4);

  const int NR = B_N * S_N;
  proj_q_fused<<<dim3(NR / 64), 256, 0, stream>>>(queries_it, Wq_it, bq_it, qit, qmask);
  proj_k_fused<<<dim3(NR / 64), 256, 0, stream>>>(keys_it, Wk_it, bk_it, Wv, bv, kit, vt, kmask);
  proj_ctx<<<dim3(NR / 64), 256, 0, stream>>>(queries_ctx, Wq_ctx, bq_ctx, qctx);
  proj_ctx<<<dim3(NR / 64), 256, 0, stream>>>(keys_ctx, Wk_ctx, bk_ctx, kctx);

  attn_kernel<<<dim3(B_N * (S_N / 64)), 256, 0, stream>>>(
      qit, kit, qctx, kctx, vt, noise, sigma, qmask, kmask, queries_it,
      W1, b1, W2, b2, out);
}